// Round 1
// baseline (435.949 us; speedup 1.0000x reference)
//
#include <hip/hip_runtime.h>
#include <math.h>

#define BATCH 64
#define CD 256
#define NX 784
#define TRIU_N 32896
#define MSZ 65536           // elems per swizzled 256x256 matrix
#define REG_STRIDE 1032     // 128 rows * 8 elems + 8 pad (bank-conflict break)
#define ARR_STRIDE 4128     // 4 regions
#define BUF_STRIDE 16512    // 4 arrays (Ahi,Alo,Bhi,Blo)
#define NBLKS 256           // grid = 4 tiles x 64 batches = #CUs (all co-resident)
#define NBARS 7

typedef unsigned short ushort_t;
typedef unsigned int uint_t;
typedef __attribute__((ext_vector_type(8))) short short8;
typedef __attribute__((ext_vector_type(8))) unsigned short ushort8;
typedef __attribute__((ext_vector_type(16))) float floatx16;

__device__ __forceinline__ ushort_t f2bf(float x) {
    uint_t u = __float_as_uint(x);
    u += 0x7fffu + ((u >> 16) & 1u);
    return (ushort_t)(u >> 16);
}
__device__ __forceinline__ float bf2f(ushort_t h) {
    return __uint_as_float(((uint_t)h) << 16);
}
__device__ __forceinline__ void split2(float x, ushort_t& h, ushort_t& l) {
    h = f2bf(x);
    l = f2bf(x - bf2f(h));
}

// swizzled offset of element (r,c) within one 256x256 matrix
__device__ __forceinline__ int swoff(int r, int c) {
    int p = r >> 7, s = (c >> 5) & 7, ks = (c >> 4) & 1, kh = (c >> 3) & 1;
    return ((((p * 8 + s) * 2 + ks) * 2 + kh) * 128 + (r & 127)) * 8 + (c & 7);
}

// ---------------------------------------------------------------------------
// Device-wide barrier: monotonic per-slot counters (no in-kernel reset; the
// launcher memsets the 7 slots each graph replay). Release: __threadfence
// (buffer_wbl2) before the agent-scope add; acquire: __threadfence
// (buffer_inv) after the spin. Relaxed agent atomic loads bypass the local
// (non-coherent) XCD L2, so polls always see remote arrivals. All 256 blocks
// are co-resident (grid == #CUs, <=2 blocks/CU fit) -> spin cannot deadlock.
__device__ __forceinline__ void gbar(unsigned* bars, int idx) {
    __syncthreads();
    if (threadIdx.x == 0) {
        __threadfence();
        __hip_atomic_fetch_add(&bars[idx], 1u, __ATOMIC_RELAXED, __HIP_MEMORY_SCOPE_AGENT);
        while (__hip_atomic_load(&bars[idx], __ATOMIC_RELAXED, __HIP_MEMORY_SCOPE_AGENT) < NBLKS)
            __builtin_amdgcn_s_sleep(1);
        __threadfence();
    }
    __syncthreads();
}

// ---------------------------------------------------------------------------
// One BK=32 stage: wave computes 2 quadrants (wr, wcp*2+{0,1}) of 32x32.
// 12 ds_read_b128 + 12 MFMA per wave per stage.
__device__ __forceinline__ void mfma_stage8(const ushort_t* us, int bufbase,
                                            int wr, int wcp, int khalf, int lrow,
                                            floatx16* acc) {
    #pragma unroll
    for (int ks = 0; ks < 2; ++ks) {
        const int rid = ks * 2 + khalf;
        const ushort_t* rb = us + bufbase + rid * REG_STRIDE + lrow * 8;
        short8 aH = *(const short8*)(rb + wr * 256);
        short8 aL = *(const short8*)(rb + ARR_STRIDE + wr * 256);
        #pragma unroll
        for (int cq = 0; cq < 2; ++cq) {
            const int col = wcp * 2 + cq;
            short8 bH = *(const short8*)(rb + 2 * ARR_STRIDE + col * 256);
            short8 bL = *(const short8*)(rb + 3 * ARR_STRIDE + col * 256);
            acc[cq] = __builtin_amdgcn_mfma_f32_32x32x16_bf16(aH, bH, acc[cq], 0, 0, 0);
            acc[cq] = __builtin_amdgcn_mfma_f32_32x32x16_bf16(aH, bL, acc[cq], 0, 0, 0);
            acc[cq] = __builtin_amdgcn_mfma_f32_32x32x16_bf16(aL, bH, acc[cq], 0, 0, 0);
        }
    }
}

// ---------------------------------------------------------------------------
__device__ __forceinline__ void ns_prefetch(const ushort_t* const* arrp, ushort_t* us,
                                            int wv, int lane, int s, int buf) {
    #pragma unroll
    for (int j = 0; j < 4; ++j) {
        int ck = wv * 4 + j;
        int arr = ck >> 3, rid = (ck >> 1) & 3, half = ck & 1;
        const ushort_t* g = arrp[arr] + s * 4096 + rid * 1024 + half * 512 + lane * 8;
        ushort_t* l = us + buf * BUF_STRIDE + arr * ARR_STRIDE + rid * REG_STRIDE + half * 512;
        __builtin_amdgcn_global_load_lds(
            (const __attribute__((address_space(1))) unsigned int*)g,
            (__attribute__((address_space(3))) unsigned int*)l, 16, 0, 0);
    }
}

// accumulator -> fsmem bounce (stride 129 -> conflict-free)
__device__ __forceinline__ void acc_bounce(float* fsmem, const floatx16* acc,
                                           int wr, int wcp, int khalf, int lrow) {
    __syncthreads();
    #pragma unroll
    for (int cq = 0; cq < 2; ++cq)
        #pragma unroll
        for (int i = 0; i < 16; ++i) {
            int rl = (i & 3) + ((i >> 2) << 3) + (khalf << 2);
            fsmem[(wr * 32 + rl) * 129 + (wcp * 2 + cq) * 32 + lrow] = acc[cq][i];
        }
    __syncthreads();
}

// ---------------------------------------------------------------------------
// Gram phase: Sigma = X X^T / n - m m^T, with row-sum (means) accumulation
// folded into the staging loads (each block computes the means for BOTH of
// its panels -> its epilogue depends only on its own writes; duplicate
// writers store bit-identical values).
__device__ __forceinline__ void gram_phase(float* fsmem, const float* __restrict__ X,
                                           float* __restrict__ means,
                                           ushort_t* __restrict__ Gh, ushort_t* __restrict__ Gl,
                                           int tile, int bb) {
    ushort_t* us = (ushort_t*)fsmem;
    const int rowBase = (tile >> 1) * 128, colBase = (tile & 1) * 128;
    const int tid = threadIdx.x, lane = tid & 63, wv = tid >> 6;
    const int wr = wv >> 1, wcp = wv & 1;
    const int khalf = lane >> 5, lrow = lane & 31;
    const float* Xb = X + (size_t)bb * CD * NX;

    floatx16 acc[2];
    #pragma unroll
    for (int cq = 0; cq < 2; ++cq)
        #pragma unroll
        for (int i = 0; i < 16; ++i) acc[cq][i] = 0.f;

    int side[2], srow[2], skq[2];
    #pragma unroll
    for (int q = 0; q < 2; ++q) {
        int gid = q * 512 + tid;
        side[q] = gid >> 9;               // q=0 -> A(row) panel, q=1 -> B(col) panel
        srow[q] = (gid >> 2) & 127;
        skq[q]  = gid & 3;
    }
    float rs[2] = {0.f, 0.f};             // per-thread partial row sums

    float4 cur[2][2];
    // prologue: load + convert + write stage 0
    #pragma unroll
    for (int q = 0; q < 2; ++q) {
        int gk = skq[q] * 8;
        const float* p = Xb + (size_t)((side[q] ? colBase : rowBase) + srow[q]) * NX + gk;
        cur[q][0] = *(const float4*)p;
        cur[q][1] = *(const float4*)(p + 4);
    }
    #pragma unroll
    for (int q = 0; q < 2; ++q) {
        float f[8] = {cur[q][0].x, cur[q][0].y, cur[q][0].z, cur[q][0].w,
                      cur[q][1].x, cur[q][1].y, cur[q][1].z, cur[q][1].w};
        rs[q] += ((f[0] + f[1]) + (f[2] + f[3])) + ((f[4] + f[5]) + (f[6] + f[7]));
        uint_t hp[4], lp[4];
        #pragma unroll
        for (int i = 0; i < 4; ++i) {
            ushort_t h0, l0, h1, l1;
            split2(f[2*i], h0, l0); split2(f[2*i+1], h1, l1);
            hp[i] = (uint_t)h0 | ((uint_t)h1 << 16);
            lp[i] = (uint_t)l0 | ((uint_t)l1 << 16);
        }
        int base = (side[q] * 2) * ARR_STRIDE + skq[q] * REG_STRIDE + srow[q] * 8;
        *(uint4*)(us + base)              = make_uint4(hp[0], hp[1], hp[2], hp[3]);
        *(uint4*)(us + base + ARR_STRIDE) = make_uint4(lp[0], lp[1], lp[2], lp[3]);
    }

    for (int s = 0; s < 25; ++s) {
        __syncthreads();
        bool more = (s + 1 < 25);
        if (more) {
            #pragma unroll
            for (int q = 0; q < 2; ++q) {
                int gk = (s + 1) * 32 + skq[q] * 8;
                if (gk < NX) {
                    const float* p = Xb + (size_t)((side[q] ? colBase : rowBase) + srow[q]) * NX + gk;
                    cur[q][0] = *(const float4*)p;
                    cur[q][1] = *(const float4*)(p + 4);
                } else {
                    cur[q][0] = make_float4(0.f, 0.f, 0.f, 0.f);
                    cur[q][1] = make_float4(0.f, 0.f, 0.f, 0.f);
                }
            }
        }
        mfma_stage8(us, (s & 1) * BUF_STRIDE, wr, wcp, khalf, lrow, acc);
        if (more) {
            int buf = (s + 1) & 1;
            #pragma unroll
            for (int q = 0; q < 2; ++q) {
                float f[8] = {cur[q][0].x, cur[q][0].y, cur[q][0].z, cur[q][0].w,
                              cur[q][1].x, cur[q][1].y, cur[q][1].z, cur[q][1].w};
                rs[q] += ((f[0] + f[1]) + (f[2] + f[3])) + ((f[4] + f[5]) + (f[6] + f[7]));
                uint_t hp[4], lp[4];
                #pragma unroll
                for (int i = 0; i < 4; ++i) {
                    ushort_t h0, l0, h1, l1;
                    split2(f[2*i], h0, l0); split2(f[2*i+1], h1, l1);
                    hp[i] = (uint_t)h0 | ((uint_t)h1 << 16);
                    lp[i] = (uint_t)l0 | ((uint_t)l1 << 16);
                }
                int base = buf * BUF_STRIDE + (side[q] * 2) * ARR_STRIDE
                         + skq[q] * REG_STRIDE + srow[q] * 8;
                *(uint4*)(us + base)              = make_uint4(hp[0], hp[1], hp[2], hp[3]);
                *(uint4*)(us + base + ARR_STRIDE) = make_uint4(lp[0], lp[1], lp[2], lp[3]);
            }
        }
    }

    // means: reduce the 4 lanes (skq 0..3) sharing a row; write both panels.
    {
        float r0 = rs[0], r1 = rs[1];
        r0 += __shfl_xor(r0, 1, 64); r0 += __shfl_xor(r0, 2, 64);
        r1 += __shfl_xor(r1, 1, 64); r1 += __shfl_xor(r1, 2, 64);
        if ((tid & 3) == 0) {
            int rr = tid >> 2;                       // 0..127
            means[bb * CD + rowBase + rr] = r0 * (1.0f / NX);
            means[bb * CD + colBase + rr] = r1 * (1.0f / NX);
        }
    }

    acc_bounce(fsmem, acc, wr, wcp, khalf, lrow);    // syncthreads also drains means stores
    const int rloc = tid & 127;
    const int r = rowBase + rloc;
    const float mr = means[bb * CD + r];
    #pragma unroll
    for (int gi = 0; gi < 4; ++gi) {
        int g = (tid >> 7) + gi * 4;
        int c0 = colBase + g * 8;
        int so = swoff(r, c0);
        ushort8 hh, ll;
        #pragma unroll
        for (int j = 0; j < 8; ++j) {
            float v = fsmem[rloc * 129 + g * 8 + j] * (1.0f / NX) - mr * means[bb * CD + c0 + j];
            ushort_t h, l; split2(v, h, l);
            hh[j] = h; ll[j] = l;
        }
        *(ushort8*)(Gh + (size_t)bb * MSZ + so) = hh;
        *(ushort8*)(Gl + (size_t)bb * MSZ + so) = ll;
    }
}

// ---------------------------------------------------------------------------
// Every block redundantly computes its batch's trace (256 diag elems of the
// complete Sigma, valid after the post-gram grid barrier) -> it, st stay in
// registers; no second barrier, no itr/str round-trip.
__device__ __forceinline__ void trace_phase(float* fsmem,
                                            const ushort_t* __restrict__ Gh,
                                            const ushort_t* __restrict__ Gl,
                                            int bb, float& it, float& st) {
    const int tid = threadIdx.x;
    float s = 0.f;
    if (tid < 256) {
        size_t d = (size_t)bb * MSZ + swoff(tid, tid);
        s = bf2f(Gh[d]) + bf2f(Gl[d]);
    }
    for (int off = 32; off; off >>= 1) s += __shfl_down(s, off, 64);
    if (tid < 256 && (tid & 63) == 0) fsmem[tid >> 6] = s;
    __syncthreads();
    float t = fsmem[0] + fsmem[1] + fsmem[2] + fsmem[3];
    it = 1.0f / t;
    st = sqrtf(t);
    __syncthreads();   // protect fsmem before the next phase's prefetch
}

// ---------------------------------------------------------------------------
// One NS GEMM step on swizzled split-bf16 operands.
// MODE 0: O1 = acc
// MODE 1: O1 = 1.5*M - 0.5*acc
// MODE 2: y = 1.5*it*M - 0.5*it^2*acc; O1=y; O2 = 1.5*I - 0.5*y
// MODE 3: out_triu = st * (1.5*M - 0.5*acc)
template<int MODE>
__device__ __forceinline__ void ns_step(float* fsmem, int tile, int bb,
    const ushort_t* __restrict__ Ah, const ushort_t* __restrict__ Al,
    const ushort_t* __restrict__ Bh, const ushort_t* __restrict__ Bl,
    const ushort_t* __restrict__ Mh, const ushort_t* __restrict__ Ml,
    float it, float st,
    ushort_t* __restrict__ O1h, ushort_t* __restrict__ O1l,
    ushort_t* __restrict__ O2h, ushort_t* __restrict__ O2l,
    float* __restrict__ outT) {
    const int rowBase = (tile >> 1) * 128, colBase = (tile & 1) * 128;
    if (MODE == 3 && rowBase > colBase) return;   // last step only: safe to skip out
    ushort_t* us = (ushort_t*)fsmem;
    const size_t mb = (size_t)bb * MSZ;
    const int tid = threadIdx.x, lane = tid & 63, wv = tid >> 6;
    const int wr = wv >> 1, wcp = wv & 1;
    const int khalf = lane >> 5, lrow = lane & 31;
    const ushort_t* arrp[4] = {
        Ah + mb + (size_t)(rowBase >> 7) * 32768,
        Al + mb + (size_t)(rowBase >> 7) * 32768,
        Bh + mb + (size_t)(colBase >> 7) * 32768,
        Bl + mb + (size_t)(colBase >> 7) * 32768 };

    floatx16 acc[2];
    #pragma unroll
    for (int cq = 0; cq < 2; ++cq)
        #pragma unroll
        for (int i = 0; i < 16; ++i) acc[cq][i] = 0.f;

    ns_prefetch(arrp, us, wv, lane, 0, 0);
    #pragma unroll
    for (int s = 0; s < 8; ++s) {
        __syncthreads();
        if (s < 7) ns_prefetch(arrp, us, wv, lane, s + 1, (s + 1) & 1);
        mfma_stage8(us, (s & 1) * BUF_STRIDE, wr, wcp, khalf, lrow, acc);
    }

    acc_bounce(fsmem, acc, wr, wcp, khalf, lrow);
    const int rloc = tid & 127;
    const int r = rowBase + rloc;
    #pragma unroll
    for (int gi = 0; gi < 4; ++gi) {
        int g = (tid >> 7) + gi * 4;
        int c0 = colBase + g * 8;
        int so = swoff(r, c0);
        float v[8];
        #pragma unroll
        for (int j = 0; j < 8; ++j) v[j] = fsmem[rloc * 129 + g * 8 + j];
        if (MODE == 0) {
            ushort8 hh, ll;
            #pragma unroll
            for (int j = 0; j < 8; ++j) {
                ushort_t h, l; split2(v[j], h, l);
                hh[j] = h; ll[j] = l;
            }
            *(ushort8*)(O1h + mb + so) = hh;
            *(ushort8*)(O1l + mb + so) = ll;
        } else {
            ushort8 mh = *(const ushort8*)(Mh + mb + so);
            ushort8 mlv = *(const ushort8*)(Ml + mb + so);
            if (MODE == 1) {
                ushort8 hh, ll;
                #pragma unroll
                for (int j = 0; j < 8; ++j) {
                    float m = bf2f(mh[j]) + bf2f(mlv[j]);
                    float y = fmaf(1.5f, m, -0.5f * v[j]);
                    ushort_t h, l; split2(y, h, l);
                    hh[j] = h; ll[j] = l;
                }
                *(ushort8*)(O1h + mb + so) = hh;
                *(ushort8*)(O1l + mb + so) = ll;
            } else if (MODE == 2) {
                ushort8 yh, yl, zh, zl;
                #pragma unroll
                for (int j = 0; j < 8; ++j) {
                    float m = bf2f(mh[j]) + bf2f(mlv[j]);
                    float y = 1.5f * it * m - 0.5f * it * it * v[j];
                    float z = ((r == c0 + j) ? 1.5f : 0.f) - 0.5f * y;
                    ushort_t h, l;
                    split2(y, h, l); yh[j] = h; yl[j] = l;
                    split2(z, h, l); zh[j] = h; zl[j] = l;
                }
                *(ushort8*)(O1h + mb + so) = yh;
                *(ushort8*)(O1l + mb + so) = yl;
                *(ushort8*)(O2h + mb + so) = zh;
                *(ushort8*)(O2l + mb + so) = zl;
            } else {
                int tb = r * CD - (r * (r - 1)) / 2 - r;
                #pragma unroll
                for (int j = 0; j < 8; ++j) {
                    float m = bf2f(mh[j]) + bf2f(mlv[j]);
                    float y = fmaf(1.5f, m, -0.5f * v[j]);
                    int c = c0 + j;
                    if (c >= r) outT[(size_t)bb * TRIU_N + tb + c] = st * y;
                }
            }
        }
    }
}

// ---------------------------------------------------------------------------
// The entire op after the X read: gram -> trace -> 7 NS GEMM steps, one
// persistent kernel, grid barriers between producer/consumer steps.
__global__ __launch_bounds__(512, 1)
void fused_k(const float* __restrict__ X,
             ushort_t* __restrict__ S0h, ushort_t* __restrict__ S0l,
             ushort_t* __restrict__ S1h, ushort_t* __restrict__ S1l,
             ushort_t* __restrict__ S2h, ushort_t* __restrict__ S2l,
             ushort_t* __restrict__ S3h, ushort_t* __restrict__ S3l,
             float* __restrict__ means, float* __restrict__ outT,
             unsigned* __restrict__ bars) {
    __shared__ __align__(16) float fsmem[16512];   // 66 KB
    const int tile = blockIdx.x, bb = blockIdx.y;

    // Sigma -> S0 (means folded in)
    gram_phase(fsmem, X, means, S0h, S0l, tile, bb);
    gbar(bars, 0);

    float it, st;
    trace_phase(fsmem, S0h, S0l, bb, it, st);

    // iter1 (scale folded): Y1 -> S1, Z1 -> S2
    ns_step<2>(fsmem, tile, bb, S0h, S0l, S0h, S0l, S0h, S0l, it, 0.f,
               S1h, S1l, S2h, S2l, nullptr);
    gbar(bars, 1);
    // T1 = Z1*Y1 -> S3
    ns_step<0>(fsmem, tile, bb, S2h, S2l, S1h, S1l, nullptr, nullptr, 0.f, 0.f,
               S3h, S3l, nullptr, nullptr, nullptr);
    gbar(bars, 2);
    // Y2 = 1.5Y1 - 0.5 Y1*T1 -> S0
    ns_step<1>(fsmem, tile, bb, S1h, S1l, S3h, S3l, S1h, S1l, 0.f, 0.f,
               S0h, S0l, nullptr, nullptr, nullptr);
    gbar(bars, 3);
    // T2 = Z1*Y2 -> S3
    ns_step<0>(fsmem, tile, bb, S2h, S2l, S0h, S0l, nullptr, nullptr, 0.f, 0.f,
               S3h, S3l, nullptr, nullptr, nullptr);
    gbar(bars, 4);
    // Z2 = 1.5Z1 - 0.5 T2*Z1 -> S1
    ns_step<1>(fsmem, tile, bb, S3h, S3l, S2h, S2l, S2h, S2l, 0.f, 0.f,
               S1h, S1l, nullptr, nullptr, nullptr);
    gbar(bars, 5);
    // T3 = Z2*Y2 -> S3
    ns_step<0>(fsmem, tile, bb, S1h, S1l, S0h, S0l, nullptr, nullptr, 0.f, 0.f,
               S3h, S3l, nullptr, nullptr, nullptr);
    gbar(bars, 6);
    // out = st * (1.5 Y2 - 0.5 Y2*T3), triu-packed
    ns_step<3>(fsmem, tile, bb, S0h, S0l, S3h, S3l, S0h, S0l, 0.f, st,
               nullptr, nullptr, nullptr, nullptr, outT);
}

// ---------------------------------------------------------------------------
extern "C" void kernel_launch(void* const* d_in, const int* in_sizes, int n_in,
                              void* d_out, int out_size, void* d_ws, size_t ws_size,
                              hipStream_t stream) {
    const float* x = (const float*)d_in[0];
    float* out = (float*)d_out;
    char* ws = (char*)d_ws;
    const size_t HS = (size_t)BATCH * MSZ * 2;   // bytes per matrix array (8 MB)
    ushort_t* S0h = (ushort_t*)(ws + 0 * HS);
    ushort_t* S0l = (ushort_t*)(ws + 1 * HS);
    ushort_t* S1h = (ushort_t*)(ws + 2 * HS);
    ushort_t* S1l = (ushort_t*)(ws + 3 * HS);
    ushort_t* S2h = (ushort_t*)(ws + 4 * HS);
    ushort_t* S2l = (ushort_t*)(ws + 5 * HS);
    ushort_t* S3h = (ushort_t*)(ws + 6 * HS);
    ushort_t* S3l = (ushort_t*)(ws + 7 * HS);
    float* means = (float*)(ws + 8 * HS);
    unsigned* bars = (unsigned*)(means + BATCH * CD);

    // re-zero barrier slots every launch/replay (captured as a memset node)
    hipMemsetAsync(bars, 0, NBARS * sizeof(unsigned), stream);
    fused_k<<<dim3(4, BATCH), 512, 0, stream>>>(x, S0h, S0l, S1h, S1l,
                                                S2h, S2l, S3h, S3l,
                                                means, out, bars);
}

// Round 2
// 245.132 us; speedup vs baseline: 1.7784x; 1.7784x over previous
//
#include <hip/hip_runtime.h>
#include <math.h>

#define BATCH 64
#define CD 256
#define NX 784
#define TRIU_N 32896
#define MSZ 65536           // elems per swizzled 256x256 matrix
#define REG_STRIDE 1032     // 128 rows * 8 elems + 8 pad (bank-conflict break)
#define ARR_STRIDE 4128     // 4 regions
#define BUF_STRIDE 16512    // 4 arrays (Ahi,Alo,Bhi,Blo)

typedef unsigned short ushort_t;
typedef unsigned int uint_t;
typedef __attribute__((ext_vector_type(8))) short short8;
typedef __attribute__((ext_vector_type(8))) unsigned short ushort8;
typedef __attribute__((ext_vector_type(16))) float floatx16;

__device__ __forceinline__ ushort_t f2bf(float x) {
    uint_t u = __float_as_uint(x);
    u += 0x7fffu + ((u >> 16) & 1u);
    return (ushort_t)(u >> 16);
}
__device__ __forceinline__ float bf2f(ushort_t h) {
    return __uint_as_float(((uint_t)h) << 16);
}
__device__ __forceinline__ void split2(float x, ushort_t& h, ushort_t& l) {
    h = f2bf(x);
    l = f2bf(x - bf2f(h));
}

// swizzled offset of element (r,c) within one 256x256 matrix
__device__ __forceinline__ int swoff(int r, int c) {
    int p = r >> 7, s = (c >> 5) & 7, ks = (c >> 4) & 1, kh = (c >> 3) & 1;
    return ((((p * 8 + s) * 2 + ks) * 2 + kh) * 128 + (r & 127)) * 8 + (c & 7);
}

// raw workgroup barrier: NO compiler-inserted vmcnt(0) drain. Caller must
// have issued the appropriate s_waitcnt (lgkmcnt for ds_writes, counted
// vmcnt for global_load_lds) before calling. sched_barrier(0) pins the
// scheduler so ds_reads/MFMA can't be hoisted above the barrier (rule #18).
__device__ __forceinline__ void rawbar() {
    __builtin_amdgcn_s_barrier();
    __builtin_amdgcn_sched_barrier(0);
}

// ---------------------------------------------------------------------------
// One BK=32 stage: wave computes 2 quadrants (wr, wcp*2+{0,1}) of 32x32.
// 12 ds_read_b128 + 12 MFMA per wave per stage. setprio(1) wrapped (T5).
__device__ __forceinline__ void mfma_stage8(const ushort_t* us, int bufbase,
                                            int wr, int wcp, int khalf, int lrow,
                                            floatx16* acc) {
    __builtin_amdgcn_s_setprio(1);
    #pragma unroll
    for (int ks = 0; ks < 2; ++ks) {
        const int rid = ks * 2 + khalf;
        const ushort_t* rb = us + bufbase + rid * REG_STRIDE + lrow * 8;
        short8 aH = *(const short8*)(rb + wr * 256);
        short8 aL = *(const short8*)(rb + ARR_STRIDE + wr * 256);
        #pragma unroll
        for (int cq = 0; cq < 2; ++cq) {
            const int col = wcp * 2 + cq;
            short8 bH = *(const short8*)(rb + 2 * ARR_STRIDE + col * 256);
            short8 bL = *(const short8*)(rb + 3 * ARR_STRIDE + col * 256);
            acc[cq] = __builtin_amdgcn_mfma_f32_32x32x16_bf16(aH, bH, acc[cq], 0, 0, 0);
            acc[cq] = __builtin_amdgcn_mfma_f32_32x32x16_bf16(aH, bL, acc[cq], 0, 0, 0);
            acc[cq] = __builtin_amdgcn_mfma_f32_32x32x16_bf16(aL, bH, acc[cq], 0, 0, 0);
        }
    }
    __builtin_amdgcn_s_setprio(0);
}

// accumulator -> fsmem bounce (stride 129 -> conflict-free).
// Uses plain __syncthreads (full drain is fine/required here).
__device__ __forceinline__ void acc_bounce(float* fsmem, const floatx16* acc,
                                           int wr, int wcp, int khalf, int lrow) {
    __syncthreads();
    #pragma unroll
    for (int cq = 0; cq < 2; ++cq)
        #pragma unroll
        for (int i = 0; i < 16; ++i) {
            int rl = (i & 3) + ((i >> 2) << 3) + (khalf << 2);
            fsmem[(wr * 32 + rl) * 129 + (wcp * 2 + cq) * 32 + lrow] = acc[cq][i];
        }
    __syncthreads();
}

// ---------------------------------------------------------------------------
// Gram: Sigma = X X^T / n - m m^T. Means fused (row sums accumulated during
// staging; each block computes means for BOTH of its panels -> epilogue
// depends only on own writes). Raw barriers: only lgkmcnt(0) before s_barrier
// (ds_writes visible); X loads are register loads tracked by reg deps, so no
// per-stage vmcnt(0) drain -- the round-0/1 per-stage stall.
__global__ __launch_bounds__(512, 1)
void gram_mfma(const float* __restrict__ X, float* __restrict__ means,
               ushort_t* __restrict__ Gh, ushort_t* __restrict__ Gl) {
    __shared__ __align__(16) float fsmem[16512];   // 66 KB: 2 staging bufs OR epilogue tile
    ushort_t* us = (ushort_t*)fsmem;
    const int bb = blockIdx.y, tile = blockIdx.x;
    const int rowBase = (tile >> 1) * 128, colBase = (tile & 1) * 128;
    const int tid = threadIdx.x, lane = tid & 63, wv = tid >> 6;
    const int wr = wv >> 1, wcp = wv & 1;
    const int khalf = lane >> 5, lrow = lane & 31;
    const float* Xb = X + (size_t)bb * CD * NX;

    floatx16 acc[2];
    #pragma unroll
    for (int cq = 0; cq < 2; ++cq)
        #pragma unroll
        for (int i = 0; i < 16; ++i) acc[cq][i] = 0.f;

    int side[2], srow[2], skq[2];
    #pragma unroll
    for (int q = 0; q < 2; ++q) {
        int gid = q * 512 + tid;
        side[q] = gid >> 9;
        srow[q] = (gid >> 2) & 127;
        skq[q]  = gid & 3;
    }
    float rs[2] = {0.f, 0.f};             // per-thread partial row sums

    float4 cur[2][2];
    // prologue: load + convert + write stage 0
    #pragma unroll
    for (int q = 0; q < 2; ++q) {
        int gk = skq[q] * 8;
        const float* p = Xb + (size_t)((side[q] ? colBase : rowBase) + srow[q]) * NX + gk;
        cur[q][0] = *(const float4*)p;
        cur[q][1] = *(const float4*)(p + 4);
    }
    #pragma unroll
    for (int q = 0; q < 2; ++q) {
        float f[8] = {cur[q][0].x, cur[q][0].y, cur[q][0].z, cur[q][0].w,
                      cur[q][1].x, cur[q][1].y, cur[q][1].z, cur[q][1].w};
        rs[q] += ((f[0] + f[1]) + (f[2] + f[3])) + ((f[4] + f[5]) + (f[6] + f[7]));
        uint_t hp[4], lp[4];
        #pragma unroll
        for (int i = 0; i < 4; ++i) {
            ushort_t h0, l0, h1, l1;
            split2(f[2*i], h0, l0); split2(f[2*i+1], h1, l1);
            hp[i] = (uint_t)h0 | ((uint_t)h1 << 16);
            lp[i] = (uint_t)l0 | ((uint_t)l1 << 16);
        }
        int base = (side[q] * 2) * ARR_STRIDE + skq[q] * REG_STRIDE + srow[q] * 8;
        *(uint4*)(us + base)              = make_uint4(hp[0], hp[1], hp[2], hp[3]);
        *(uint4*)(us + base + ARR_STRIDE) = make_uint4(lp[0], lp[1], lp[2], lp[3]);
    }

    for (int s = 0; s < 25; ++s) {
        asm volatile("s_waitcnt lgkmcnt(0)" ::: "memory");  // my ds_writes done
        rawbar();                                            // buf s&1 ready for all
        bool more = (s < 24);
        if (more) {
            // issue next-stage X loads right after the barrier; they complete
            // under the MFMA stage below (reg-dep tracked, no explicit wait)
            #pragma unroll
            for (int q = 0; q < 2; ++q) {
                int gk = (s + 1) * 32 + skq[q] * 8;
                if (gk < NX) {
                    const float* p = Xb + (size_t)((side[q] ? colBase : rowBase) + srow[q]) * NX + gk;
                    cur[q][0] = *(const float4*)p;
                    cur[q][1] = *(const float4*)(p + 4);
                } else {
                    cur[q][0] = make_float4(0.f, 0.f, 0.f, 0.f);
                    cur[q][1] = make_float4(0.f, 0.f, 0.f, 0.f);
                }
            }
        }
        mfma_stage8(us, (s & 1) * BUF_STRIDE, wr, wcp, khalf, lrow, acc);
        if (more) {
            int buf = (s + 1) & 1;
            #pragma unroll
            for (int q = 0; q < 2; ++q) {
                float f[8] = {cur[q][0].x, cur[q][0].y, cur[q][0].z, cur[q][0].w,
                              cur[q][1].x, cur[q][1].y, cur[q][1].z, cur[q][1].w};
                rs[q] += ((f[0] + f[1]) + (f[2] + f[3])) + ((f[4] + f[5]) + (f[6] + f[7]));
                uint_t hp[4], lp[4];
                #pragma unroll
                for (int i = 0; i < 4; ++i) {
                    ushort_t h0, l0, h1, l1;
                    split2(f[2*i], h0, l0); split2(f[2*i+1], h1, l1);
                    hp[i] = (uint_t)h0 | ((uint_t)h1 << 16);
                    lp[i] = (uint_t)l0 | ((uint_t)l1 << 16);
                }
                int base = buf * BUF_STRIDE + (side[q] * 2) * ARR_STRIDE
                         + skq[q] * REG_STRIDE + srow[q] * 8;
                *(uint4*)(us + base)              = make_uint4(hp[0], hp[1], hp[2], hp[3]);
                *(uint4*)(us + base + ARR_STRIDE) = make_uint4(lp[0], lp[1], lp[2], lp[3]);
            }
        }
    }

    // means: reduce the 4 lanes (skq 0..3) sharing a row; write both panels.
    {
        float r0 = rs[0], r1 = rs[1];
        r0 += __shfl_xor(r0, 1, 64); r0 += __shfl_xor(r0, 2, 64);
        r1 += __shfl_xor(r1, 1, 64); r1 += __shfl_xor(r1, 2, 64);
        if ((tid & 3) == 0) {
            int rr = tid >> 2;                       // 0..127
            means[bb * CD + rowBase + rr] = r0 * (1.0f / NX);
            means[bb * CD + colBase + rr] = r1 * (1.0f / NX);
        }
    }

    acc_bounce(fsmem, acc, wr, wcp, khalf, lrow);    // full-drain syncthreads flushes means stores
    const int rloc = tid & 127;
    const int r = rowBase + rloc;
    const float mr = means[bb * CD + r];
    #pragma unroll
    for (int gi = 0; gi < 4; ++gi) {
        int g = (tid >> 7) + gi * 4;
        int c0 = colBase + g * 8;
        int so = swoff(r, c0);
        ushort8 hh, ll;
        #pragma unroll
        for (int j = 0; j < 8; ++j) {
            float v = fsmem[rloc * 129 + g * 8 + j] * (1.0f / NX) - mr * means[bb * CD + c0 + j];
            ushort_t h, l; split2(v, h, l);
            hh[j] = h; ll[j] = l;
        }
        *(ushort8*)(Gh + (size_t)bb * MSZ + so) = hh;
        *(ushort8*)(Gl + (size_t)bb * MSZ + so) = ll;
    }
}

// ---------------------------------------------------------------------------
__global__ __launch_bounds__(64)
void trace_k(const ushort_t* __restrict__ Gh, const ushort_t* __restrict__ Gl,
             float* __restrict__ itr, float* __restrict__ str_) {
    int b = blockIdx.x, lane = threadIdx.x;
    float s = 0.f;
    #pragma unroll
    for (int i = 0; i < 4; ++i) {
        int c = lane + i * 64;
        size_t d = (size_t)b * MSZ + swoff(c, c);
        s += bf2f(Gh[d]) + bf2f(Gl[d]);
    }
    for (int off = 32; off; off >>= 1) s += __shfl_down(s, off, 64);
    if (lane == 0) { itr[b] = 1.0f / s; str_[b] = sqrtf(s); }
}

// ---------------------------------------------------------------------------
__device__ __forceinline__ void ns_prefetch(const ushort_t* const* arrp, ushort_t* us,
                                            int wv, int lane, int s, int buf) {
    #pragma unroll
    for (int j = 0; j < 4; ++j) {
        int ck = wv * 4 + j;
        int arr = ck >> 3, rid = (ck >> 1) & 3, half = ck & 1;
        const ushort_t* g = arrp[arr] + s * 4096 + rid * 1024 + half * 512 + lane * 8;
        ushort_t* l = us + buf * BUF_STRIDE + arr * ARR_STRIDE + rid * REG_STRIDE + half * 512;
        __builtin_amdgcn_global_load_lds(
            (const __attribute__((address_space(1))) unsigned int*)g,
            (__attribute__((address_space(3))) unsigned int*)l, 16, 0, 0);
    }
}

// NS GEMM on swizzled split-bf16 operands. 4-deep LDS pipeline (T3+T4):
// prologue issues stages 0..2; each stage waits ONLY the oldest stage's
// 4 loads (vmcnt counted), raw-barriers, computes, then issues stage s+3
// into the buffer freed at stage s-1. No full vmcnt drain in the loop.
// MODE 0: O1 = acc
// MODE 1: O1 = 1.5*M - 0.5*acc
// MODE 2: y = 1.5*it*M - 0.5*it^2*acc; O1=y; O2 = 1.5*I - 0.5*y
// MODE 3: out_triu = st * (1.5*M - 0.5*acc)
template<int MODE>
__global__ __launch_bounds__(512, 1)
void ns_mfma(const ushort_t* __restrict__ Ah, const ushort_t* __restrict__ Al,
             const ushort_t* __restrict__ Bh, const ushort_t* __restrict__ Bl,
             const ushort_t* __restrict__ Mh, const ushort_t* __restrict__ Ml,
             const float* __restrict__ itr, const float* __restrict__ str_,
             ushort_t* __restrict__ O1h, ushort_t* __restrict__ O1l,
             ushort_t* __restrict__ O2h, ushort_t* __restrict__ O2l,
             float* __restrict__ outT) {
    const int tile = blockIdx.x;
    const int rowBase = (tile >> 1) * 128, colBase = (tile & 1) * 128;
    if (MODE == 3 && rowBase > colBase) return;
    __shared__ __align__(16) float fsmem[33024];   // 132 KB: 4 staging bufs; epilogue overlays first 66 KB
    ushort_t* us = (ushort_t*)fsmem;
    const int bb = blockIdx.y;
    const size_t mb = (size_t)bb * MSZ;
    const int tid = threadIdx.x, lane = tid & 63, wv = tid >> 6;
    const int wr = wv >> 1, wcp = wv & 1;
    const int khalf = lane >> 5, lrow = lane & 31;
    const ushort_t* arrp[4] = {
        Ah + mb + (size_t)(rowBase >> 7) * 32768,
        Al + mb + (size_t)(rowBase >> 7) * 32768,
        Bh + mb + (size_t)(colBase >> 7) * 32768,
        Bl + mb + (size_t)(colBase >> 7) * 32768 };

    floatx16 acc[2];
    #pragma unroll
    for (int cq = 0; cq < 2; ++cq)
        #pragma unroll
        for (int i = 0; i < 16; ++i) acc[cq][i] = 0.f;

    // prologue: 3 stages in flight (12 loads/wave outstanding)
    ns_prefetch(arrp, us, wv, lane, 0, 0);
    ns_prefetch(arrp, us, wv, lane, 1, 1);
    ns_prefetch(arrp, us, wv, lane, 2, 2);
    #pragma unroll
    for (int s = 0; s < 8; ++s) {
        // wait: stage s's 4 loads complete for THIS wave (leave newer in flight)
        if (s <= 5)      asm volatile("s_waitcnt vmcnt(8)" ::: "memory");
        else if (s == 6) asm volatile("s_waitcnt vmcnt(4)" ::: "memory");
        else             asm volatile("s_waitcnt vmcnt(0)" ::: "memory");
        rawbar();                           // all waves' stage-s loads landed
        mfma_stage8(us, (s & 3) * BUF_STRIDE, wr, wcp, khalf, lrow, acc);
        if (s < 5)                           // refill buffer freed at stage s-1
            ns_prefetch(arrp, us, wv, lane, s + 3, (s + 3) & 3);
    }

    acc_bounce(fsmem, acc, wr, wcp, khalf, lrow);
    const int rloc = tid & 127;
    const int r = rowBase + rloc;
    float it = 0.f, st = 0.f;
    if (MODE == 2) it = itr[bb];
    if (MODE == 3) st = str_[bb];
    #pragma unroll
    for (int gi = 0; gi < 4; ++gi) {
        int g = (tid >> 7) + gi * 4;
        int c0 = colBase + g * 8;
        int so = swoff(r, c0);
        float v[8];
        #pragma unroll
        for (int j = 0; j < 8; ++j) v[j] = fsmem[rloc * 129 + g * 8 + j];
        if (MODE == 0) {
            ushort8 hh, ll;
            #pragma unroll
            for (int j = 0; j < 8; ++j) {
                ushort_t h, l; split2(v[j], h, l);
                hh[j] = h; ll[j] = l;
            }
            *(ushort8*)(O1h + mb + so) = hh;
            *(ushort8*)(O1l + mb + so) = ll;
        } else {
            ushort8 mh = *(const ushort8*)(Mh + mb + so);
            ushort8 mlv = *(const ushort8*)(Ml + mb + so);
            if (MODE == 1) {
                ushort8 hh, ll;
                #pragma unroll
                for (int j = 0; j < 8; ++j) {
                    float m = bf2f(mh[j]) + bf2f(mlv[j]);
                    float y = fmaf(1.5f, m, -0.5f * v[j]);
                    ushort_t h, l; split2(y, h, l);
                    hh[j] = h; ll[j] = l;
                }
                *(ushort8*)(O1h + mb + so) = hh;
                *(ushort8*)(O1l + mb + so) = ll;
            } else if (MODE == 2) {
                ushort8 yh, yl, zh, zl;
                #pragma unroll
                for (int j = 0; j < 8; ++j) {
                    float m = bf2f(mh[j]) + bf2f(mlv[j]);
                    float y = 1.5f * it * m - 0.5f * it * it * v[j];
                    float z = ((r == c0 + j) ? 1.5f : 0.f) - 0.5f * y;
                    ushort_t h, l;
                    split2(y, h, l); yh[j] = h; yl[j] = l;
                    split2(z, h, l); zh[j] = h; zl[j] = l;
                }
                *(ushort8*)(O1h + mb + so) = yh;
                *(ushort8*)(O1l + mb + so) = yl;
                *(ushort8*)(O2h + mb + so) = zh;
                *(ushort8*)(O2l + mb + so) = zl;
            } else {
                int tb = r * CD - (r * (r - 1)) / 2 - r;
                #pragma unroll
                for (int j = 0; j < 8; ++j) {
                    float m = bf2f(mh[j]) + bf2f(mlv[j]);
                    float y = fmaf(1.5f, m, -0.5f * v[j]);
                    int c = c0 + j;
                    if (c >= r) outT[(size_t)bb * TRIU_N + tb + c] = st * y;
                }
            }
        }
    }
}

// ---------------------------------------------------------------------------
extern "C" void kernel_launch(void* const* d_in, const int* in_sizes, int n_in,
                              void* d_out, int out_size, void* d_ws, size_t ws_size,
                              hipStream_t stream) {
    const float* x = (const float*)d_in[0];
    float* out = (float*)d_out;
    char* ws = (char*)d_ws;
    const size_t HS = (size_t)BATCH * MSZ * 2;   // bytes per matrix array (8 MB)
    ushort_t* S0h = (ushort_t*)(ws + 0 * HS);
    ushort_t* S0l = (ushort_t*)(ws + 1 * HS);
    ushort_t* S1h = (ushort_t*)(ws + 2 * HS);
    ushort_t* S1l = (ushort_t*)(ws + 3 * HS);
    ushort_t* S2h = (ushort_t*)(ws + 4 * HS);
    ushort_t* S2l = (ushort_t*)(ws + 5 * HS);
    ushort_t* S3h = (ushort_t*)(ws + 6 * HS);
    ushort_t* S3l = (ushort_t*)(ws + 7 * HS);
    float* means = (float*)(ws + 8 * HS);
    float* itr = means + BATCH * CD;
    float* str_ = itr + BATCH;

    dim3 gG(4, BATCH);
    gram_mfma<<<gG, 512, 0, stream>>>(x, means, S0h, S0l);              // Sigma -> S0 (means fused)
    trace_k<<<BATCH, 64, 0, stream>>>(S0h, S0l, itr, str_);
    // iter1 (scale folded): Y1 -> S1, Z1 -> S2
    ns_mfma<2><<<gG, 512, 0, stream>>>(S0h, S0l, S0h, S0l, S0h, S0l,
                                       itr, nullptr, S1h, S1l, S2h, S2l, nullptr);
    // T1 = Z1*Y1 -> S3
    ns_mfma<0><<<gG, 512, 0, stream>>>(S2h, S2l, S1h, S1l, nullptr, nullptr,
                                       nullptr, nullptr, S3h, S3l, nullptr, nullptr, nullptr);
    // Y2 = 1.5Y1 - 0.5 Y1*T1 -> S0
    ns_mfma<1><<<gG, 512, 0, stream>>>(S1h, S1l, S3h, S3l, S1h, S1l,
                                       nullptr, nullptr, S0h, S0l, nullptr, nullptr, nullptr);
    // T2 = Z1*Y2 -> S3
    ns_mfma<0><<<gG, 512, 0, stream>>>(S2h, S2l, S0h, S0l, nullptr, nullptr,
                                       nullptr, nullptr, S3h, S3l, nullptr, nullptr, nullptr);
    // Z2 = 1.5Z1 - 0.5 T2*Z1 -> S1  (M = B = Z1)
    ns_mfma<1><<<gG, 512, 0, stream>>>(S3h, S3l, S2h, S2l, S2h, S2l,
                                       nullptr, nullptr, S1h, S1l, nullptr, nullptr, nullptr);
    // T3 = Z2*Y2 -> S3
    ns_mfma<0><<<gG, 512, 0, stream>>>(S1h, S1l, S0h, S0l, nullptr, nullptr,
                                       nullptr, nullptr, S3h, S3l, nullptr, nullptr, nullptr);
    // out = st * (1.5 Y2 - 0.5 Y2*T3), triu-packed
    ns_mfma<3><<<gG, 512, 0, stream>>>(S0h, S0l, S3h, S3l, S0h, S0l,
                                       nullptr, str_, nullptr, nullptr, nullptr, nullptr, out);
}